// Round 4
// baseline (185.638 us; speedup 1.0000x reference)
//
#include <hip/hip_runtime.h>
#include <hip/hip_bf16.h>

// Problem constants (match reference)
#define WORLD   4
#define S_SEEDS 16000
#define FANOUT  16
#define F_FRONT (S_SEEDS * (FANOUT + 1))   // 272000 frontier rows / partition
#define E_EDGES (S_SEEDS * FANOUT)         // 256000 edges / partition
#define D       128
#define M_ROWS  (WORLD * S_SEEDS)          // 64000 output rows
#define N_EDGES (WORLD * E_EDGES)          // 1024000 edges total
#define CAP     64                         // per-dst bucket capacity (Poisson(16): P(>64)~3e-20)

typedef __attribute__((ext_vector_type(8))) short bf16x8;
typedef __attribute__((ext_vector_type(4))) float f32x4;

__device__ __forceinline__ unsigned short f2bf(float f) {
    union { float f; unsigned u; } v; v.f = f;
    unsigned r = v.u + 0x7FFFu + ((v.u >> 16) & 1u);   // RNE
    return (unsigned short)(r >> 16);
}

// ---------------------------------------------------------------------------
// Kernel 1a: bucket fill. One thread per edge; int atomic gets the slot.
// ---------------------------------------------------------------------------
__global__ __launch_bounds__(256) void fill_k(
    const int* __restrict__ coo_row,
    const int* __restrict__ coo_col,
    int*       __restrict__ cnt,
    int*       __restrict__ elist)
{
    unsigned e = blockIdx.x * 256u + threadIdx.x;
    unsigned part = e / E_EDGES;
    unsigned dst  = part * S_SEEDS + (unsigned)coo_row[e];
    unsigned src  = part * F_FRONT + (unsigned)coo_col[e];
    int slot = atomicAdd(&cnt[dst], 1);
    if (slot < CAP)
        elist[(unsigned long)dst * CAP + slot] = (int)src;
}

// ---------------------------------------------------------------------------
// Kernel 1b: per-dst gather, uniform version. ONE FULL WAVE per dst row;
// lane l owns channels 2l,2l+1 (float2). Single 8-deep masked loop:
//  - two int4 index loads per chunk (garbage beyond deg clamped to row 0
//    BEFORE address formation -> poison-safe),
//  - 8 independent 512B row loads per chunk,
//  - masked accumulate via fmaf (same cost as add).
// No divergent tails: trip count is wave-uniform (one dst per wave).
// Mean written as packed 2xbf16 per lane (256B per row).
// ---------------------------------------------------------------------------
__global__ __launch_bounds__(256) void gather_k(
    const float* __restrict__ feat,
    const int*   __restrict__ cnt,
    const int*   __restrict__ elist,
    unsigned short* __restrict__ hb)   // [M_ROWS][D] bf16
{
    const int t   = threadIdx.x;
    const int dst = blockIdx.x * 4 + (t >> 6);   // one wave per dst
    const int l   = t & 63;

    int deg = cnt[dst];
    if (deg > CAP) deg = CAP;   // safety (never expected)
    const int* el = elist + (long)dst * CAP;
    const float2* F2 = reinterpret_cast<const float2*>(feat);  // row stride 64

    float a0 = 0.f, a1 = 0.f, b0 = 0.f, b1 = 0.f;
    float c0 = 0.f, c1 = 0.f, d0 = 0.f, d1 = 0.f;

    for (int e = 0; e < deg; e += 8) {
        int4 i0 = *reinterpret_cast<const int4*>(el + e);
        int4 i1 = *reinterpret_cast<const int4*>(el + e + 4);
        // slot 0 always valid (e < deg); clamp the rest
        int  j0 = i0.x;
        int  j1 = (e + 1 < deg) ? i0.y : 0;
        int  j2 = (e + 2 < deg) ? i0.z : 0;
        int  j3 = (e + 3 < deg) ? i0.w : 0;
        int  j4 = (e + 4 < deg) ? i1.x : 0;
        int  j5 = (e + 5 < deg) ? i1.y : 0;
        int  j6 = (e + 6 < deg) ? i1.z : 0;
        int  j7 = (e + 7 < deg) ? i1.w : 0;
        float m1 = (e + 1 < deg) ? 1.f : 0.f;
        float m2 = (e + 2 < deg) ? 1.f : 0.f;
        float m3 = (e + 3 < deg) ? 1.f : 0.f;
        float m4 = (e + 4 < deg) ? 1.f : 0.f;
        float m5 = (e + 5 < deg) ? 1.f : 0.f;
        float m6 = (e + 6 < deg) ? 1.f : 0.f;
        float m7 = (e + 7 < deg) ? 1.f : 0.f;

        float2 v0 = F2[(long)j0 * 64 + l];
        float2 v1 = F2[(long)j1 * 64 + l];
        float2 v2 = F2[(long)j2 * 64 + l];
        float2 v3 = F2[(long)j3 * 64 + l];
        float2 v4 = F2[(long)j4 * 64 + l];
        float2 v5 = F2[(long)j5 * 64 + l];
        float2 v6 = F2[(long)j6 * 64 + l];
        float2 v7 = F2[(long)j7 * 64 + l];

        a0 += v0.x;              a1 += v0.y;
        b0 = fmaf(v1.x, m1, b0); b1 = fmaf(v1.y, m1, b1);
        c0 = fmaf(v2.x, m2, c0); c1 = fmaf(v2.y, m2, c1);
        d0 = fmaf(v3.x, m3, d0); d1 = fmaf(v3.y, m3, d1);
        a0 = fmaf(v4.x, m4, a0); a1 = fmaf(v4.y, m4, a1);
        b0 = fmaf(v5.x, m5, b0); b1 = fmaf(v5.y, m5, b1);
        c0 = fmaf(v6.x, m6, c0); c1 = fmaf(v6.y, m6, c1);
        d0 = fmaf(v7.x, m7, d0); d1 = fmaf(v7.y, m7, d1);
    }

    float hx = (a0 + b0 + c0 + d0) * (1.0f / FANOUT);
    float hy = (a1 + b1 + c1 + d1) * (1.0f / FANOUT);
    unsigned pk = (unsigned)f2bf(hx) | ((unsigned)f2bf(hy) << 16);
    reinterpret_cast<unsigned*>(hb + (long)dst * D)[l] = pk;
}

// ---------------------------------------------------------------------------
// Kernel 2: fused finish:
//   out[r] = hb[r] @ Wn^T + feat_dst[r] @ Ws^T + b
// GEMM: [M x 256] @ [256 x 128] via mfma_f32_16x16x32_bf16.
// hb already bf16 + pre-normalized; feat_dst converted on the fly.
// ---------------------------------------------------------------------------
__global__ __launch_bounds__(256) void finish_k(
    const float*          __restrict__ feat,
    const unsigned short* __restrict__ hb,
    const float*          __restrict__ wn,
    const float*          __restrict__ wself,
    const float*          __restrict__ bias,
    float*                __restrict__ out)
{
    // [kstep 8][ctile 8][lane 64] -> one 16B bf16x8 B-fragment per entry
    __shared__ uint4 wlds[8 * 8 * 64];

    const int t = threadIdx.x;

    // ---- stage weights: global fp32 -> bf16 fragments in LDS ----
    for (int idx = t; idx < 8 * 8 * 64; idx += 256) {
        int l  = idx & 63;
        int c  = (idx >> 6) & 7;
        int s  = idx >> 9;
        int o  = c * 16 + (l & 15);          // output channel (B col)
        int kb = s * 32 + (l >> 4) * 8;      // k base (8 contiguous k per lane)
        const float* src = (kb < 128) ? (wn + o * 128 + kb)
                                      : (wself + o * 128 + (kb - 128));
        float4 p0 = reinterpret_cast<const float4*>(src)[0];
        float4 p1 = reinterpret_cast<const float4*>(src)[1];
        uint4 w;
        w.x = (unsigned)f2bf(p0.x) | ((unsigned)f2bf(p0.y) << 16);
        w.y = (unsigned)f2bf(p0.z) | ((unsigned)f2bf(p0.w) << 16);
        w.z = (unsigned)f2bf(p1.x) | ((unsigned)f2bf(p1.y) << 16);
        w.w = (unsigned)f2bf(p1.z) | ((unsigned)f2bf(p1.w) << 16);
        wlds[idx] = w;
    }
    __syncthreads();

    const int wave = t >> 6;
    const int l    = t & 63;
    const int l15  = l & 15;
    const int lhi  = l >> 4;

    for (int p = 0; p < 2; ++p) {
        const int rowbase = blockIdx.x * 128 + p * 64 + wave * 16;
        const int arow    = rowbase + l15;          // A row this lane loads

        const unsigned short* hrow = hb + (long)arow * D + lhi * 8;
        int part = arow / S_SEEDS;
        int idx  = arow - part * S_SEEDS;
        const float* xrow = feat + ((long)part * F_FRONT + idx) * D + lhi * 8;

        f32x4 acc[8] = {};

#pragma unroll
        for (int s = 0; s < 8; ++s) {
            bf16x8 af;
            if (s < 4) {
                af = *reinterpret_cast<const bf16x8*>(hrow + s * 32);
            } else {
                const float* asrc = xrow + (s - 4) * 32;
                float4 a0 = reinterpret_cast<const float4*>(asrc)[0];
                float4 a1 = reinterpret_cast<const float4*>(asrc)[1];
                af[0] = (short)f2bf(a0.x);
                af[1] = (short)f2bf(a0.y);
                af[2] = (short)f2bf(a0.z);
                af[3] = (short)f2bf(a0.w);
                af[4] = (short)f2bf(a1.x);
                af[5] = (short)f2bf(a1.y);
                af[6] = (short)f2bf(a1.z);
                af[7] = (short)f2bf(a1.w);
            }
#pragma unroll
            for (int c = 0; c < 8; ++c) {
                bf16x8 bf = *reinterpret_cast<const bf16x8*>(&wlds[(s * 8 + c) * 64 + l]);
                acc[c] = __builtin_amdgcn_mfma_f32_16x16x32_bf16(af, bf, acc[c], 0, 0, 0);
            }
        }

        // C/D layout (verified m89): col = lane&15, row = (lane>>4)*4 + reg
#pragma unroll
        for (int c = 0; c < 8; ++c) {
            const int col = c * 16 + l15;
            const float bv = bias[col];
#pragma unroll
            for (int j = 0; j < 4; ++j) {
                const int r = rowbase + lhi * 4 + j;
                out[(long)r * D + col] = acc[c][j] + bv;
            }
        }
    }
}

// ---------------------------------------------------------------------------
// Fallback finish (in-place h in d_out as f32), for small-ws path.
// ---------------------------------------------------------------------------
__global__ __launch_bounds__(256) void finish_f32_k(
    const float* __restrict__ feat,
    const float* __restrict__ wn,
    const float* __restrict__ wself,
    const float* __restrict__ bias,
    float*       __restrict__ io,
    float hscale)
{
    __shared__ uint4 wlds[8 * 8 * 64];
    const int t = threadIdx.x;
    for (int idx = t; idx < 8 * 8 * 64; idx += 256) {
        int l  = idx & 63;
        int c  = (idx >> 6) & 7;
        int s  = idx >> 9;
        int o  = c * 16 + (l & 15);
        int kb = s * 32 + (l >> 4) * 8;
        const float* src = (kb < 128) ? (wn + o * 128 + kb)
                                      : (wself + o * 128 + (kb - 128));
        float4 p0 = reinterpret_cast<const float4*>(src)[0];
        float4 p1 = reinterpret_cast<const float4*>(src)[1];
        uint4 w;
        w.x = (unsigned)f2bf(p0.x) | ((unsigned)f2bf(p0.y) << 16);
        w.y = (unsigned)f2bf(p0.z) | ((unsigned)f2bf(p0.w) << 16);
        w.z = (unsigned)f2bf(p1.x) | ((unsigned)f2bf(p1.y) << 16);
        w.w = (unsigned)f2bf(p1.z) | ((unsigned)f2bf(p1.w) << 16);
        wlds[idx] = w;
    }
    __syncthreads();

    const int wave = t >> 6;
    const int l    = t & 63;
    const int l15  = l & 15;
    const int lhi  = l >> 4;

    for (int p = 0; p < 2; ++p) {
        const int rowbase = blockIdx.x * 128 + p * 64 + wave * 16;
        const int arow    = rowbase + l15;
        const float* hrow = io + (long)arow * D + lhi * 8;
        int part = arow / S_SEEDS;
        int idx  = arow - part * S_SEEDS;
        const float* xrow = feat + ((long)part * F_FRONT + idx) * D + lhi * 8;
        f32x4 acc[8] = {};
#pragma unroll
        for (int s = 0; s < 8; ++s) {
            const float* asrc = (s < 4) ? (hrow + s * 32) : (xrow + (s - 4) * 32);
            const float scale = (s < 4) ? hscale : 1.0f;
            float4 a0 = reinterpret_cast<const float4*>(asrc)[0];
            float4 a1 = reinterpret_cast<const float4*>(asrc)[1];
            bf16x8 af;
            af[0] = (short)f2bf(a0.x * scale);
            af[1] = (short)f2bf(a0.y * scale);
            af[2] = (short)f2bf(a0.z * scale);
            af[3] = (short)f2bf(a0.w * scale);
            af[4] = (short)f2bf(a1.x * scale);
            af[5] = (short)f2bf(a1.y * scale);
            af[6] = (short)f2bf(a1.z * scale);
            af[7] = (short)f2bf(a1.w * scale);
#pragma unroll
            for (int c = 0; c < 8; ++c) {
                bf16x8 bf = *reinterpret_cast<const bf16x8*>(&wlds[(s * 8 + c) * 64 + l]);
                acc[c] = __builtin_amdgcn_mfma_f32_16x16x32_bf16(af, bf, acc[c], 0, 0, 0);
            }
        }
#pragma unroll
        for (int c = 0; c < 8; ++c) {
            const int col = c * 16 + l15;
            const float bv = bias[col];
#pragma unroll
            for (int j = 0; j < 4; ++j) {
                const int r = rowbase + lhi * 4 + j;
                io[(long)r * D + col] = acc[c][j] + bv;
            }
        }
    }
}

// Fallback gather writing f32 h (into d_out)
__global__ __launch_bounds__(256) void gather_f32_k(
    const float* __restrict__ feat,
    const int*   __restrict__ cnt,
    const int*   __restrict__ elist,
    float*       __restrict__ h)
{
    const int t   = threadIdx.x;
    const int dst = blockIdx.x * 8 + (t >> 5);
    const int l   = t & 31;
    int deg = cnt[dst];
    if (deg > CAP) deg = CAP;
    const int* el = elist + (long)dst * CAP;
    const float4* F4 = reinterpret_cast<const float4*>(feat);
    f32x4 acc = {0.f, 0.f, 0.f, 0.f};
    for (int e = 0; e < deg; ++e) {
        float4 v = F4[(long)el[e] * 32 + l];
        acc[0] += v.x; acc[1] += v.y; acc[2] += v.z; acc[3] += v.w;
    }
    float4 r;
    r.x = acc[0] * (1.0f / FANOUT);
    r.y = acc[1] * (1.0f / FANOUT);
    r.z = acc[2] * (1.0f / FANOUT);
    r.w = acc[3] * (1.0f / FANOUT);
    reinterpret_cast<float4*>(h)[(long)dst * 32 + l] = r;
}

// Last-resort atomic scatter (round-1 path)
__global__ __launch_bounds__(256) void scatter_k(
    const float* __restrict__ feat,
    const int*   __restrict__ coo_row,
    const int*   __restrict__ coo_col,
    float*       __restrict__ hsum)
{
    unsigned g = blockIdx.x * 256u + threadIdx.x;
    unsigned e = g >> 5;
    unsigned l = g & 31u;
    unsigned part = e / E_EDGES;
    unsigned dst  = part * S_SEEDS + (unsigned)coo_row[e];
    unsigned long src = (unsigned long)part * F_FRONT + (unsigned)coo_col[e];
    float4 v = reinterpret_cast<const float4*>(feat)[src * 32u + l];
    float* o = hsum + (unsigned long)dst * D + l * 4u;
    atomicAdd(o + 0, v.x);
    atomicAdd(o + 1, v.y);
    atomicAdd(o + 2, v.z);
    atomicAdd(o + 3, v.w);
}

extern "C" void kernel_launch(void* const* d_in, const int* in_sizes, int n_in,
                              void* d_out, int out_size, void* d_ws, size_t ws_size,
                              hipStream_t stream) {
    const float* feat    = (const float*)d_in[0];
    const int*   coo_row = (const int*)d_in[1];
    const int*   coo_col = (const int*)d_in[2];
    const float* wn      = (const float*)d_in[3];
    const float* wself   = (const float*)d_in[4];
    const float* bias    = (const float*)d_in[5];
    float*       out     = (float*)d_out;

    const size_t csr_bytes = (size_t)M_ROWS * sizeof(int)
                           + (size_t)M_ROWS * CAP * sizeof(int);
    const size_t hb_bytes  = (size_t)M_ROWS * D * sizeof(unsigned short);

    if (ws_size >= csr_bytes + hb_bytes) {
        int* cnt   = (int*)d_ws;
        int* elist = cnt + M_ROWS;
        unsigned short* hb = (unsigned short*)(elist + (size_t)M_ROWS * CAP);

        hipMemsetAsync(cnt, 0, (size_t)M_ROWS * sizeof(int), stream);
        fill_k<<<N_EDGES / 256, 256, 0, stream>>>(coo_row, coo_col, cnt, elist);
        gather_k<<<M_ROWS / 4, 256, 0, stream>>>(feat, cnt, elist, hb);
        finish_k<<<M_ROWS / 128, 256, 0, stream>>>(feat, hb, wn, wself, bias, out);
    } else if (ws_size >= csr_bytes) {
        int* cnt   = (int*)d_ws;
        int* elist = cnt + M_ROWS;
        hipMemsetAsync(cnt, 0, (size_t)M_ROWS * sizeof(int), stream);
        fill_k<<<N_EDGES / 256, 256, 0, stream>>>(coo_row, coo_col, cnt, elist);
        gather_f32_k<<<M_ROWS / 8, 256, 0, stream>>>(feat, cnt, elist, out);
        finish_f32_k<<<M_ROWS / 128, 256, 0, stream>>>(feat, wn, wself, bias, out, 1.0f);
    } else {
        hipMemsetAsync(out, 0, (size_t)M_ROWS * D * sizeof(float), stream);
        scatter_k<<<N_EDGES / 8, 256, 0, stream>>>(feat, coo_row, coo_col, out);
        finish_f32_k<<<M_ROWS / 128, 256, 0, stream>>>(feat, wn, wself, bias, out,
                                                       1.0f / FANOUT);
    }
}